// Round 3
// baseline (499.245 us; speedup 1.0000x reference)
//
#include <hip/hip_runtime.h>

// Problem constants
#define BB 8
#define PP 5000
#define DD 64
#define NBP (BB * PP)        // 40000 pairs
#define NPOSC 20000
#define GRID_POS (NPOSC / 4) // 5000 blocks x 4 waves = one wave per position
#define CHUNK 80             // scan: 256 threads x 80 = 20480 >= NPOSC

static __device__ __forceinline__ float4 f4add(float4 a, float4 b) {
    return make_float4(a.x + b.x, a.y + b.y, a.z + b.z, a.w + b.w);
}

// ---------------------------------------------------------------------------
// Prep 1: exact-position histogram (20000 counters, avg contention 2)
__global__ __launch_bounds__(256) void hist_kernel(
    const int* __restrict__ positions, int* __restrict__ hist)
{
    const int tid = blockIdx.x * 256 + threadIdx.x;
    if (tid < NBP) atomicAdd(&hist[positions[tid]], 1);
}

// Prep 2: exclusive scan over 20000 counts -> offs[0..20000] (+sentinel) and
// a mutable cursor copy for the scatter pass. Single block, two-pass (no big
// per-thread arrays -> no spills).
__global__ __launch_bounds__(256) void scan_kernel(
    const int* __restrict__ hist, int* __restrict__ offs,
    int* __restrict__ cursor)
{
    __shared__ int lsum[256];
    const int t = threadIdx.x;
    const int base = t * CHUNK;
    int run = 0;
    for (int j = 0; j < CHUNK; ++j) {
        const int idx = base + j;
        if (idx < NPOSC) run += hist[idx];
    }
    lsum[t] = run;
    __syncthreads();
    if (t == 0) {
        int acc = 0;
        for (int i = 0; i < 256; ++i) { const int x = lsum[i]; lsum[i] = acc; acc += x; }
    }
    __syncthreads();
    int acc = lsum[t];
    for (int j = 0; j < CHUNK; ++j) {
        const int idx = base + j;
        if (idx < NPOSC) {
            offs[idx]   = acc;
            cursor[idx] = acc;
            acc += hist[idx];
        }
    }
    if (t == 255) offs[NPOSC] = acc;   // thread 255 owns no real entries -> acc == NBP
}

// Prep 3: scatter pair ids into position-grouped order (inverse index)
__global__ __launch_bounds__(256) void scatter_kernel(
    const int* __restrict__ positions, int* __restrict__ cursor,
    int* __restrict__ order)
{
    const int tid = blockIdx.x * 256 + threadIdx.x;
    if (tid < NBP) {
        const int idx = atomicAdd(&cursor[positions[tid]], 1);
        order[idx] = tid;
    }
}

// ---------------------------------------------------------------------------
// Main: one 64-lane wave per POSITION. The wave loads the 16 KB kernel row
// once and serves every (b,p) pair sharing that position (avg 2.3, Poisson2).
// Wave id == position, XCD-swizzled (5000 = 8 x 625) so each XCD streams a
// contiguous ~41 MB table range. Pairs processed 4 per chunk; chunk >1 is
// ~5% of positions and its krow re-read hits L1 (16 KB < 32 KB).
__global__ __launch_bounds__(256) void allele_embed_kernel(
    const int* __restrict__ alleles,        // [NBP, 2]
    const float* __restrict__ allele_table, // [16, 64]
    const float4* __restrict__ ktab4,       // [NPOSC * 1024]
    const float4* __restrict__ btab4,       // [NPOSC * 16]
    const int* __restrict__ offs,           // [NPOSC+1]
    const int* __restrict__ order,          // [NBP] grouped by position
    float4* __restrict__ out4)              // [NBP * 16]
{
    const int wave = threadIdx.x >> 6;
    const int lane = threadIdx.x & 63;
    const int work = (blockIdx.x & 7) * (GRID_POS / 8) + (blockIdx.x >> 3);
    const int pos  = work * 4 + wave;

    const int start = offs[pos];
    const int end   = offs[pos + 1];
    if (start == end) return;               // no pair hit this position

    const float4* __restrict__ krow = ktab4 + (size_t)pos * (DD * DD / 4);
    const int dg = lane >> 4;               // d-group 0..3
    const float4 bv = btab4[(size_t)pos * (DD / 4) + (lane & 15)];

    for (int c = start; c < end; c += 4) {
        const int m = end - c;              // pairs left in this chunk (>=1)
        const int bp0 = order[c];
        const int bp1 = (m > 1) ? order[c + 1] : bp0;
        const int bp2 = (m > 2) ? order[c + 2] : bp0;
        const int bp3 = (m > 3) ? order[c + 3] : bp0;

        // lane d holds a_j[d]; allele_table is 4 KB -> L1-resident
        const float a0 = allele_table[alleles[bp0 * 2] * DD + lane]
                       + allele_table[alleles[bp0 * 2 + 1] * DD + lane];
        const float a1 = allele_table[alleles[bp1 * 2] * DD + lane]
                       + allele_table[alleles[bp1 * 2 + 1] * DD + lane];
        const float a2 = allele_table[alleles[bp2 * 2] * DD + lane]
                       + allele_table[alleles[bp2 * 2 + 1] * DD + lane];
        const float a3 = allele_table[alleles[bp3 * 2] * DD + lane]
                       + allele_table[alleles[bp3 * 2 + 1] * DD + lane];

        float4 acc0 = make_float4(0.f, 0.f, 0.f, 0.f);
        float4 acc1 = acc0, acc2 = acc0, acc3 = acc0;
#pragma unroll
        for (int i = 0; i < 16; ++i) {
            const int d = i * 4 + dg;
            const float4 kv = krow[i * 64 + lane];
            const float d0 = __shfl(a0, d, 64);
            const float d1 = __shfl(a1, d, 64);
            const float d2 = __shfl(a2, d, 64);
            const float d3 = __shfl(a3, d, 64);
            acc0.x += d0 * kv.x; acc0.y += d0 * kv.y; acc0.z += d0 * kv.z; acc0.w += d0 * kv.w;
            acc1.x += d1 * kv.x; acc1.y += d1 * kv.y; acc1.z += d1 * kv.z; acc1.w += d1 * kv.w;
            acc2.x += d2 * kv.x; acc2.y += d2 * kv.y; acc2.z += d2 * kv.z; acc2.w += d2 * kv.w;
            acc3.x += d3 * kv.x; acc3.y += d3 * kv.y; acc3.z += d3 * kv.z; acc3.w += d3 * kv.w;
        }

        // reduce the 4 d-group partials (butterfly over lane bits 4,5)
#pragma unroll
        for (int off = 16; off <= 32; off <<= 1) {
            acc0.x += __shfl_xor(acc0.x, off, 64); acc0.y += __shfl_xor(acc0.y, off, 64);
            acc0.z += __shfl_xor(acc0.z, off, 64); acc0.w += __shfl_xor(acc0.w, off, 64);
            acc1.x += __shfl_xor(acc1.x, off, 64); acc1.y += __shfl_xor(acc1.y, off, 64);
            acc1.z += __shfl_xor(acc1.z, off, 64); acc1.w += __shfl_xor(acc1.w, off, 64);
            acc2.x += __shfl_xor(acc2.x, off, 64); acc2.y += __shfl_xor(acc2.y, off, 64);
            acc2.z += __shfl_xor(acc2.z, off, 64); acc2.w += __shfl_xor(acc2.w, off, 64);
            acc3.x += __shfl_xor(acc3.x, off, 64); acc3.y += __shfl_xor(acc3.y, off, 64);
            acc3.z += __shfl_xor(acc3.z, off, 64); acc3.w += __shfl_xor(acc3.w, off, 64);
        }

        if (lane < 16) {
            out4[(size_t)bp0 * (DD / 4) + lane] = f4add(acc0, bv);
            if (m > 1) out4[(size_t)bp1 * (DD / 4) + lane] = f4add(acc1, bv);
            if (m > 2) out4[(size_t)bp2 * (DD / 4) + lane] = f4add(acc2, bv);
            if (m > 3) out4[(size_t)bp3 * (DD / 4) + lane] = f4add(acc3, bv);
        }
    }
}

extern "C" void kernel_launch(void* const* d_in, const int* in_sizes, int n_in,
                              void* d_out, int out_size, void* d_ws, size_t ws_size,
                              hipStream_t stream) {
    const int*   alleles      = (const int*)d_in[0];
    const int*   positions    = (const int*)d_in[1];
    const float* allele_table = (const float*)d_in[2];
    const float4* ktab4       = (const float4*)d_in[3];
    const float4* btab4       = (const float4*)d_in[4];
    float4* out4              = (float4*)d_out;

    // ws layout (ints): hist[20000] | offs[20001] | cursor[20000] | order[40000]
    int* hist   = (int*)d_ws;
    int* offs   = hist + NPOSC;
    int* cursor = offs + (NPOSC + 1);
    int* order  = cursor + NPOSC;

    hipMemsetAsync(hist, 0, NPOSC * sizeof(int), stream);

    const int gprep = (NBP + 255) / 256;
    hist_kernel<<<gprep, 256, 0, stream>>>(positions, hist);
    scan_kernel<<<1, 256, 0, stream>>>(hist, offs, cursor);
    scatter_kernel<<<gprep, 256, 0, stream>>>(positions, cursor, order);

    allele_embed_kernel<<<GRID_POS, 256, 0, stream>>>(
        alleles, allele_table, ktab4, btab4, offs, order, out4);
}

// Round 4
// 442.625 us; speedup vs baseline: 1.1279x; 1.1279x over previous
//
#include <hip/hip_runtime.h>

// Problem constants
#define BB 8
#define PP 5000
#define DD 64
#define NBP (BB * PP)        // 40000 pairs
#define NPOSC 20000
#define SLOTS 16             // direct-slot inverse index width (P[count>16]~1e-9, overflow handled)
#define GRID_POS (NPOSC / 4) // 5000 blocks x 4 waves = one wave per position

static __device__ __forceinline__ float4 f4add(float4 a, float4 b) {
    return make_float4(a.x + b.x, a.y + b.y, a.z + b.z, a.w + b.w);
}

// ---------------------------------------------------------------------------
// Prep (single kernel, no scan): atomically claim a slot in the per-position
// list. Overflow (k >= SLOTS) goes to a global overflow list -- correctness
// guaranteed for ANY position distribution.
__global__ __launch_bounds__(256) void claim_kernel(
    const int* __restrict__ positions,
    int* __restrict__ cnt,        // [NPOSC] zeroed
    int* __restrict__ ovf_cnt,    // [1] zeroed
    int* __restrict__ order2,     // [NPOSC * SLOTS]
    int* __restrict__ ovf)        // [NBP]
{
    const int tid = blockIdx.x * 256 + threadIdx.x;
    if (tid < NBP) {
        const int p = positions[tid];
        const int k = atomicAdd(&cnt[p], 1);
        if (k < SLOTS) order2[p * SLOTS + k] = tid;
        else           ovf[atomicAdd(ovf_cnt, 1)] = tid;
    }
}

// ---------------------------------------------------------------------------
// Main: one 64-lane wave per POSITION, ascending position order per XCD
// (5000 = 8 x 625 swizzle) -> each XCD streams a contiguous ~41 MB slab of
// kernel_table, each needed 16 KB row fetched exactly once.
//   - lane d holds a_j[d] (allele_table is 4 KB, L1-resident)
//   - kernel row: 16 coalesced dwordx4 sweeps (1 KB / instruction)
//   - acc_j[e-quad] += a_j[d] * K[d][e-quad], a_j[d] via __shfl
//   - butterfly reduce lanes differing in bits 4,5; lanes 0..15 store 256 B
__global__ __launch_bounds__(256) void allele_embed_kernel(
    const int* __restrict__ alleles,        // [NBP, 2]
    const float* __restrict__ allele_table, // [16, 64]
    const float4* __restrict__ ktab4,       // [NPOSC * 1024]
    const float4* __restrict__ btab4,       // [NPOSC * 16]
    const int* __restrict__ cnt,            // [NPOSC]
    const int* __restrict__ order2,         // [NPOSC * SLOTS]
    float4* __restrict__ out4)              // [NBP * 16]
{
    const int wave = threadIdx.x >> 6;
    const int lane = threadIdx.x & 63;
    const int work = (blockIdx.x & 7) * (GRID_POS / 8) + (blockIdx.x >> 3);
    const int pos  = work * 4 + wave;

    int n = cnt[pos];
    if (n == 0) return;
    if (n > SLOTS) n = SLOTS;               // overflow pairs handled by tail

    const float4* __restrict__ krow = ktab4 + (size_t)pos * (DD * DD / 4);
    const int* __restrict__ slot = order2 + pos * SLOTS;
    const int dg = lane >> 4;               // d-group 0..3
    const float4 bv = btab4[(size_t)pos * (DD / 4) + (lane & 15)];

    if (n == 1) {
        // fast path: single pair (31% of active positions) -- 1/4 the VALU
        const int bp = slot[0];
        const float a = allele_table[alleles[bp * 2] * DD + lane]
                      + allele_table[alleles[bp * 2 + 1] * DD + lane];
        float4 acc = make_float4(0.f, 0.f, 0.f, 0.f);
#pragma unroll
        for (int i = 0; i < 16; ++i) {
            const float ad = __shfl(a, i * 4 + dg, 64);
            const float4 kv = krow[i * 64 + lane];
            acc.x += ad * kv.x; acc.y += ad * kv.y;
            acc.z += ad * kv.z; acc.w += ad * kv.w;
        }
#pragma unroll
        for (int off = 16; off <= 32; off <<= 1) {
            acc.x += __shfl_xor(acc.x, off, 64); acc.y += __shfl_xor(acc.y, off, 64);
            acc.z += __shfl_xor(acc.z, off, 64); acc.w += __shfl_xor(acc.w, off, 64);
        }
        if (lane < 16) out4[(size_t)bp * (DD / 4) + lane] = f4add(acc, bv);
        return;
    }

    for (int c = 0; c < n; c += 4) {
        const int m = n - c;
        const int bp0 = slot[c];
        const int bp1 = (m > 1) ? slot[c + 1] : bp0;
        const int bp2 = (m > 2) ? slot[c + 2] : bp0;
        const int bp3 = (m > 3) ? slot[c + 3] : bp0;

        const float a0 = allele_table[alleles[bp0 * 2] * DD + lane]
                       + allele_table[alleles[bp0 * 2 + 1] * DD + lane];
        const float a1 = allele_table[alleles[bp1 * 2] * DD + lane]
                       + allele_table[alleles[bp1 * 2 + 1] * DD + lane];
        const float a2 = allele_table[alleles[bp2 * 2] * DD + lane]
                       + allele_table[alleles[bp2 * 2 + 1] * DD + lane];
        const float a3 = allele_table[alleles[bp3 * 2] * DD + lane]
                       + allele_table[alleles[bp3 * 2 + 1] * DD + lane];

        float4 acc0 = make_float4(0.f, 0.f, 0.f, 0.f);
        float4 acc1 = acc0, acc2 = acc0, acc3 = acc0;
#pragma unroll
        for (int i = 0; i < 16; ++i) {
            const int d = i * 4 + dg;
            const float4 kv = krow[i * 64 + lane];
            const float d0 = __shfl(a0, d, 64);
            const float d1 = __shfl(a1, d, 64);
            const float d2 = __shfl(a2, d, 64);
            const float d3 = __shfl(a3, d, 64);
            acc0.x += d0 * kv.x; acc0.y += d0 * kv.y; acc0.z += d0 * kv.z; acc0.w += d0 * kv.w;
            acc1.x += d1 * kv.x; acc1.y += d1 * kv.y; acc1.z += d1 * kv.z; acc1.w += d1 * kv.w;
            acc2.x += d2 * kv.x; acc2.y += d2 * kv.y; acc2.z += d2 * kv.z; acc2.w += d2 * kv.w;
            acc3.x += d3 * kv.x; acc3.y += d3 * kv.y; acc3.z += d3 * kv.z; acc3.w += d3 * kv.w;
        }
#pragma unroll
        for (int off = 16; off <= 32; off <<= 1) {
            acc0.x += __shfl_xor(acc0.x, off, 64); acc0.y += __shfl_xor(acc0.y, off, 64);
            acc0.z += __shfl_xor(acc0.z, off, 64); acc0.w += __shfl_xor(acc0.w, off, 64);
            acc1.x += __shfl_xor(acc1.x, off, 64); acc1.y += __shfl_xor(acc1.y, off, 64);
            acc1.z += __shfl_xor(acc1.z, off, 64); acc1.w += __shfl_xor(acc1.w, off, 64);
            acc2.x += __shfl_xor(acc2.x, off, 64); acc2.y += __shfl_xor(acc2.y, off, 64);
            acc2.z += __shfl_xor(acc2.z, off, 64); acc2.w += __shfl_xor(acc2.w, off, 64);
            acc3.x += __shfl_xor(acc3.x, off, 64); acc3.y += __shfl_xor(acc3.y, off, 64);
            acc3.z += __shfl_xor(acc3.z, off, 64); acc3.w += __shfl_xor(acc3.w, off, 64);
        }
        if (lane < 16) {
            out4[(size_t)bp0 * (DD / 4) + lane] = f4add(acc0, bv);
            if (m > 1) out4[(size_t)bp1 * (DD / 4) + lane] = f4add(acc1, bv);
            if (m > 2) out4[(size_t)bp2 * (DD / 4) + lane] = f4add(acc2, bv);
            if (m > 3) out4[(size_t)bp3 * (DD / 4) + lane] = f4add(acc3, bv);
        }
    }
}

// ---------------------------------------------------------------------------
// Tail: overflow pairs (count > SLOTS at some position; normally ZERO).
// 256 waves stride the overflow list, R1-style one matvec per pair.
__global__ __launch_bounds__(256) void tail_kernel(
    const int* __restrict__ alleles,
    const int* __restrict__ positions,
    const float* __restrict__ allele_table,
    const float4* __restrict__ ktab4,
    const float4* __restrict__ btab4,
    const int* __restrict__ ovf_cnt,
    const int* __restrict__ ovf,
    float4* __restrict__ out4)
{
    const int nov  = *ovf_cnt;
    const int lane = threadIdx.x & 63;
    const int wid  = blockIdx.x * 4 + (threadIdx.x >> 6);
    const int dg   = lane >> 4;
    for (int i = wid; i < nov; i += 256) {
        const int bp  = ovf[i];
        const int pos = positions[bp];
        const float a = allele_table[alleles[bp * 2] * DD + lane]
                      + allele_table[alleles[bp * 2 + 1] * DD + lane];
        const float4* krow = ktab4 + (size_t)pos * (DD * DD / 4);
        float4 acc = make_float4(0.f, 0.f, 0.f, 0.f);
#pragma unroll
        for (int k = 0; k < 16; ++k) {
            const float ad = __shfl(a, k * 4 + dg, 64);
            const float4 kv = krow[k * 64 + lane];
            acc.x += ad * kv.x; acc.y += ad * kv.y;
            acc.z += ad * kv.z; acc.w += ad * kv.w;
        }
#pragma unroll
        for (int off = 16; off <= 32; off <<= 1) {
            acc.x += __shfl_xor(acc.x, off, 64); acc.y += __shfl_xor(acc.y, off, 64);
            acc.z += __shfl_xor(acc.z, off, 64); acc.w += __shfl_xor(acc.w, off, 64);
        }
        if (lane < 16) {
            const float4 bv = btab4[(size_t)pos * (DD / 4) + lane];
            out4[(size_t)bp * (DD / 4) + lane] = f4add(acc, bv);
        }
    }
}

extern "C" void kernel_launch(void* const* d_in, const int* in_sizes, int n_in,
                              void* d_out, int out_size, void* d_ws, size_t ws_size,
                              hipStream_t stream) {
    const int*   alleles      = (const int*)d_in[0];
    const int*   positions    = (const int*)d_in[1];
    const float* allele_table = (const float*)d_in[2];
    const float4* ktab4       = (const float4*)d_in[3];
    const float4* btab4       = (const float4*)d_in[4];
    float4* out4              = (float4*)d_out;

    // ws layout (ints): cnt[20000] | ovf_cnt[1] (+pad to 32) | order2[20000*16] | ovf[40000]
    int* cnt     = (int*)d_ws;
    int* ovf_cnt = cnt + NPOSC;
    int* order2  = cnt + NPOSC + 32;
    int* ovf     = order2 + NPOSC * SLOTS;

    // zero cnt + ovf_cnt (ws is re-poisoned to 0xAA before every launch)
    hipMemsetAsync(cnt, 0, (NPOSC + 32) * sizeof(int), stream);

    const int gprep = (NBP + 255) / 256;
    claim_kernel<<<gprep, 256, 0, stream>>>(positions, cnt, ovf_cnt, order2, ovf);

    allele_embed_kernel<<<GRID_POS, 256, 0, stream>>>(
        alleles, allele_table, ktab4, btab4, cnt, order2, out4);

    tail_kernel<<<64, 256, 0, stream>>>(
        alleles, positions, allele_table, ktab4, btab4, ovf_cnt, ovf, out4);
}

// Round 5
// 432.519 us; speedup vs baseline: 1.1543x; 1.0234x over previous
//
#include <hip/hip_runtime.h>

// Problem constants
#define BB 8
#define PP 5000
#define DD 64
#define NBP (BB * PP)        // 40000 pairs
#define NPOSC 20000
#define SLOTS 16             // direct-slot inverse index width; overflow handled by tail
#define GRID_POS (NPOSC / 4) // 5000 blocks x 4 waves = one wave per position

typedef float v4f __attribute__((ext_vector_type(4)));

// ---------------------------------------------------------------------------
// Prep: atomically claim a slot in the per-position list (no hist, no scan).
// 2 pairs per thread, int2 position loads. Overflow -> global list.
__global__ __launch_bounds__(256) void claim_kernel(
    const int* __restrict__ positions,
    int* __restrict__ cnt,        // [NPOSC] zeroed
    int* __restrict__ ovf_cnt,    // [1] zeroed
    int* __restrict__ order2,     // [NPOSC * SLOTS]
    int* __restrict__ ovf)        // [NBP]
{
    const int tid  = blockIdx.x * 256 + threadIdx.x;
    const int base = tid * 2;
    if (base >= NBP) return;
    const int2 p2 = ((const int2*)positions)[tid];
    {
        const int k = atomicAdd(&cnt[p2.x], 1);
        if (k < SLOTS) order2[p2.x * SLOTS + k] = base;
        else           ovf[atomicAdd(ovf_cnt, 1)] = base;
    }
    {
        const int k = atomicAdd(&cnt[p2.y], 1);
        if (k < SLOTS) order2[p2.y * SLOTS + k] = base + 1;
        else           ovf[atomicAdd(ovf_cnt, 1)] = base + 1;
    }
}

// ---------------------------------------------------------------------------
// Main: one 64-lane wave per POSITION, ascending position order per XCD
// (5000 = 8 x 625 swizzle) -> each XCD streams a contiguous ~41 MB slab of
// kernel_table; each needed 16 KB row fetched exactly once (algorithmic
// dedup). All big traffic is read-once/write-once -> non-temporal.
//   - lane d holds a_j[d] (allele_table is 4 KB, L1-resident)
//   - kernel row: 16 coalesced nt dwordx4 sweeps (1 KB / instruction)
//   - acc_j[e-quad] += a_j[d] * K[d][e-quad], a_j[d] via __shfl
//   - butterfly reduce lanes differing in bits 4,5; lanes 0..15 nt-store 256 B
__global__ __launch_bounds__(256) void allele_embed_kernel(
    const int2* __restrict__ all2,          // [NBP] (ploidy pair packed)
    const float* __restrict__ allele_table, // [16, 64]
    const v4f* __restrict__ ktab4,          // [NPOSC * 1024]
    const v4f* __restrict__ btab4,          // [NPOSC * 16]
    const int* __restrict__ cnt,            // [NPOSC]
    const int* __restrict__ order2,         // [NPOSC * SLOTS]
    v4f* __restrict__ out4)                 // [NBP * 16]
{
    const int wave = threadIdx.x >> 6;
    const int lane = threadIdx.x & 63;
    const int work = (blockIdx.x & 7) * (GRID_POS / 8) + (blockIdx.x >> 3);
    const int pos  = work * 4 + wave;

    int n = cnt[pos];
    if (n == 0) return;
    if (n > SLOTS) n = SLOTS;               // overflow pairs handled by tail

    const v4f* __restrict__ krow = ktab4 + (size_t)pos * (DD * DD / 4);
    const int* __restrict__ slot = order2 + pos * SLOTS;
    const int dg = lane >> 4;               // d-group 0..3
    const v4f bv = btab4[(size_t)pos * (DD / 4) + (lane & 15)];

    if (n == 1) {
        // fast path: single pair (~31% of active positions)
        const int bp = slot[0];
        const int2 al = all2[bp];
        const float a = allele_table[al.x * DD + lane]
                      + allele_table[al.y * DD + lane];
        v4f acc = (v4f)(0.f);
#pragma unroll
        for (int i = 0; i < 16; ++i) {
            const float ad = __shfl(a, i * 4 + dg, 64);
            const v4f kv = __builtin_nontemporal_load(&krow[i * 64 + lane]);
            acc += ad * kv;
        }
#pragma unroll
        for (int off = 16; off <= 32; off <<= 1) {
            acc.x += __shfl_xor(acc.x, off, 64); acc.y += __shfl_xor(acc.y, off, 64);
            acc.z += __shfl_xor(acc.z, off, 64); acc.w += __shfl_xor(acc.w, off, 64);
        }
        if (lane < 16)
            __builtin_nontemporal_store(acc + bv, &out4[(size_t)bp * (DD / 4) + lane]);
        return;
    }

    for (int c = 0; c < n; c += 4) {
        const int m = n - c;
        const int bp0 = slot[c];
        const int bp1 = (m > 1) ? slot[c + 1] : bp0;
        const int bp2 = (m > 2) ? slot[c + 2] : bp0;
        const int bp3 = (m > 3) ? slot[c + 3] : bp0;

        const int2 e0 = all2[bp0], e1 = all2[bp1], e2 = all2[bp2], e3 = all2[bp3];
        const float a0 = allele_table[e0.x * DD + lane] + allele_table[e0.y * DD + lane];
        const float a1 = allele_table[e1.x * DD + lane] + allele_table[e1.y * DD + lane];
        const float a2 = allele_table[e2.x * DD + lane] + allele_table[e2.y * DD + lane];
        const float a3 = allele_table[e3.x * DD + lane] + allele_table[e3.y * DD + lane];

        v4f acc0 = (v4f)(0.f), acc1 = (v4f)(0.f), acc2 = (v4f)(0.f), acc3 = (v4f)(0.f);
#pragma unroll
        for (int i = 0; i < 16; ++i) {
            const int d = i * 4 + dg;
            const v4f kv = __builtin_nontemporal_load(&krow[i * 64 + lane]);
            acc0 += __shfl(a0, d, 64) * kv;
            acc1 += __shfl(a1, d, 64) * kv;
            acc2 += __shfl(a2, d, 64) * kv;
            acc3 += __shfl(a3, d, 64) * kv;
        }
#pragma unroll
        for (int off = 16; off <= 32; off <<= 1) {
            acc0.x += __shfl_xor(acc0.x, off, 64); acc0.y += __shfl_xor(acc0.y, off, 64);
            acc0.z += __shfl_xor(acc0.z, off, 64); acc0.w += __shfl_xor(acc0.w, off, 64);
            acc1.x += __shfl_xor(acc1.x, off, 64); acc1.y += __shfl_xor(acc1.y, off, 64);
            acc1.z += __shfl_xor(acc1.z, off, 64); acc1.w += __shfl_xor(acc1.w, off, 64);
            acc2.x += __shfl_xor(acc2.x, off, 64); acc2.y += __shfl_xor(acc2.y, off, 64);
            acc2.z += __shfl_xor(acc2.z, off, 64); acc2.w += __shfl_xor(acc2.w, off, 64);
            acc3.x += __shfl_xor(acc3.x, off, 64); acc3.y += __shfl_xor(acc3.y, off, 64);
            acc3.z += __shfl_xor(acc3.z, off, 64); acc3.w += __shfl_xor(acc3.w, off, 64);
        }
        if (lane < 16) {
            __builtin_nontemporal_store(acc0 + bv, &out4[(size_t)bp0 * (DD / 4) + lane]);
            if (m > 1) __builtin_nontemporal_store(acc1 + bv, &out4[(size_t)bp1 * (DD / 4) + lane]);
            if (m > 2) __builtin_nontemporal_store(acc2 + bv, &out4[(size_t)bp2 * (DD / 4) + lane]);
            if (m > 3) __builtin_nontemporal_store(acc3 + bv, &out4[(size_t)bp3 * (DD / 4) + lane]);
        }
    }
}

// ---------------------------------------------------------------------------
// Tail: overflow pairs (count > SLOTS at some position; normally ZERO).
__global__ __launch_bounds__(256) void tail_kernel(
    const int2* __restrict__ all2,
    const int* __restrict__ positions,
    const float* __restrict__ allele_table,
    const v4f* __restrict__ ktab4,
    const v4f* __restrict__ btab4,
    const int* __restrict__ ovf_cnt,
    const int* __restrict__ ovf,
    v4f* __restrict__ out4)
{
    const int nov  = *ovf_cnt;
    const int lane = threadIdx.x & 63;
    const int wid  = blockIdx.x * 4 + (threadIdx.x >> 6);
    const int dg   = lane >> 4;
    for (int i = wid; i < nov; i += 64) {
        const int bp  = ovf[i];
        const int pos = positions[bp];
        const int2 al = all2[bp];
        const float a = allele_table[al.x * DD + lane]
                      + allele_table[al.y * DD + lane];
        const v4f* krow = ktab4 + (size_t)pos * (DD * DD / 4);
        v4f acc = (v4f)(0.f);
#pragma unroll
        for (int k = 0; k < 16; ++k) {
            const float ad = __shfl(a, k * 4 + dg, 64);
            acc += ad * krow[k * 64 + lane];
        }
#pragma unroll
        for (int off = 16; off <= 32; off <<= 1) {
            acc.x += __shfl_xor(acc.x, off, 64); acc.y += __shfl_xor(acc.y, off, 64);
            acc.z += __shfl_xor(acc.z, off, 64); acc.w += __shfl_xor(acc.w, off, 64);
        }
        if (lane < 16) {
            const v4f bv = btab4[(size_t)pos * (DD / 4) + lane];
            out4[(size_t)bp * (DD / 4) + lane] = acc + bv;
        }
    }
}

extern "C" void kernel_launch(void* const* d_in, const int* in_sizes, int n_in,
                              void* d_out, int out_size, void* d_ws, size_t ws_size,
                              hipStream_t stream) {
    const int*   alleles      = (const int*)d_in[0];
    const int*   positions    = (const int*)d_in[1];
    const float* allele_table = (const float*)d_in[2];
    const v4f*   ktab4        = (const v4f*)d_in[3];
    const v4f*   btab4        = (const v4f*)d_in[4];
    v4f* out4                 = (v4f*)d_out;
    const int2* all2          = (const int2*)alleles;

    // ws layout (ints): cnt[20000] | ovf_cnt[1] (+pad to 32) | order2[20000*16] | ovf[40000]
    int* cnt     = (int*)d_ws;
    int* ovf_cnt = cnt + NPOSC;
    int* order2  = cnt + NPOSC + 32;
    int* ovf     = order2 + NPOSC * SLOTS;

    hipMemsetAsync(cnt, 0, (NPOSC + 32) * sizeof(int), stream);

    const int gclaim = (NBP / 2 + 255) / 256;
    claim_kernel<<<gclaim, 256, 0, stream>>>(positions, cnt, ovf_cnt, order2, ovf);

    allele_embed_kernel<<<GRID_POS, 256, 0, stream>>>(
        all2, allele_table, ktab4, btab4, cnt, order2, out4);

    tail_kernel<<<16, 256, 0, stream>>>(
        all2, positions, allele_table, ktab4, btab4, ovf_cnt, ovf, out4);
}